// Round 12
// baseline (750.540 us; speedup 1.0000x reference)
//
#include <hip/hip_runtime.h>
#include <math.h>

#define NBATCH 8
#define LMAX   215
#define NND    36
#define NE     1296
#define NK     648
#define CW     860      // C = LMAX*4
#define DPE    16
#define DTR    160
#define NHEADS 4
#define DH     40
#define NHID2  256
#define NPAIR  (NBATCH*LMAX)   // 1720
#define KSPLIT 8
#define KQLEN  27              // ceil(215/8)
#define ROWS   4               // rows per GEMM tile
#define NBLK   430             // mega-kernel grid (<=512 co-resident at 2/CU)
#define MAGIC  0x5A5A5A5A

// output layout (floats)
#define OUT_TYPE (NBATCH*LMAX*DTR)              // 275200
#define OUT_TIME (OUT_TYPE + NBATCH*LMAX*NND)   // 337120
#define OUT_DIST (OUT_TIME + NBATCH*LMAX)       // 338840

// workspace layout (float offsets)
#define OFF_PE    0
#define OFF_RR    (OFF_PE + NBATCH*LMAX*DPE)
#define OFF_EW    (OFF_RR + 144)
#define OFF_BETA  (OFF_EW + NE)
#define OFF_ALPHA (OFF_BETA + NBATCH*NND*LMAX)
#define OFF_H1    (OFF_ALPHA + NBATCH*NK)
#define OFF_X     (OFF_H1 + NBATCH*NND*CW)
#define OFF_X2    (OFF_X + NBATCH*LMAX*DTR)
#define OFF_QKV   (OFF_X2 + NBATCH*LMAX*DTR)
#define OFF_TOPI  (OFF_QKV + NBATCH*LMAX*480)
#define OFF_IDX   (OFF_TOPI + NBATCH*NK)
#define OFF_LENS  (OFF_IDX + NBATCH*LMAX)
#define OFF_PART  (OFF_LENS + NBATCH)
#define OFF_CSRC  (OFF_PART + 32*KSPLIT*LMAX*42)
#define OFF_CSRL  (OFF_CSRC + NBATCH*NND)
#define OFF_WT    (OFF_CSRL + NBATCH*NND*LMAX)
// per layer: qkvT @0, outT @76800, ff1T @102400, ff2T @143360 ; stride 184320
#define OFF_BAR   (OFF_WT + 2*184320)

struct MegaArgs {
    const int* et; const float* etime; const float* Ru; const float* gs;
    const float* Winc; const float* binc; const float* mapw;
    const float* wtime; const float* wtype;
    const float* qw[2];  const float* qb[2];
    const float* ow[2];  const float* ob[2];
    const float* f1w[2]; const float* f1b[2];
    const float* f2w[2]; const float* f2b[2];
    const float* l1w[2]; const float* l1b[2];
    const float* l2w[2]; const float* l2b[2];
    float* ws; float* outp;
};

// ---- LDS phase overlays (union via char buffer) ----
struct SBeta { float rows[2][4*CW]; float pair[NPAIR]; int idx[NPAIR];
               float mapw[NND*16]; float rr[144]; float pe[NBATCH*16]; float binc[32]; }; // 44800 B
struct SPrep { int red[256]; int sidx[LMAX]; float sts[8]; };
struct STopk { float sv[NE]; float sm[NND]; };
struct SAttn { float K[KQLEN*DH]; float V[KQLEN*DH]; };
struct SH1   { int cnt; int lsrc[40]; float lew[40]; float sd[64]; };
struct SH2   { int cnt; int lsrc[40]; float lal[40]; };
struct SQkv  { float xs[ROWS*DTR]; };
struct SProj { float xs[ROWS*DTR]; float ys[ROWS*DTR]; };
struct SFf   { float xs[ROWS*DTR]; float hs[ROWS*NHID2]; float zs[ROWS*DTR]; float fin[ROWS*DTR]; };

// ---- grid barrier: one-shot counter per barrier index, monotonic generation ----
__device__ __forceinline__ void gridbar(int* cnt, int* gen, int bi) {
    __syncthreads();
    if (threadIdx.x == 0) {
        int old = __hip_atomic_fetch_add(&cnt[bi], 1, __ATOMIC_ACQ_REL, __HIP_MEMORY_SCOPE_AGENT);
        if (old == NBLK - 1) {
            __hip_atomic_store(gen, bi + 1, __ATOMIC_RELEASE, __HIP_MEMORY_SCOPE_AGENT);
        } else {
            while (__hip_atomic_load(gen, __ATOMIC_RELAXED, __HIP_MEMORY_SCOPE_AGENT) < bi + 1)
                __builtin_amdgcn_s_sleep(2);
            (void)__hip_atomic_load(gen, __ATOMIC_ACQUIRE, __HIP_MEMORY_SCOPE_AGENT);
        }
    }
    __syncthreads();
}

__device__ __forceinline__ void wave_ln_row(const float* row, int lane,
                                            const float* lnw, const float* lnb, float* dst) {
    float s = 0.f;
    for (int d = lane; d < DTR; d += 64) s += row[d];
    for (int off = 32; off > 0; off >>= 1) s += __shfl_xor(s, off);
    float mu = s / (float)DTR;
    float v = 0.f;
    for (int d = lane; d < DTR; d += 64) { float dd = row[d] - mu; v += dd * dd; }
    for (int off = 32; off > 0; off >>= 1) v += __shfl_xor(v, off);
    float rs = rsqrtf(v / (float)DTR + 1e-5f);
    for (int d = lane; d < DTR; d += 64)
        dst[d] = (row[d] - mu) * rs * lnw[d] + lnb[d];
}

__global__ __launch_bounds__(256, 2) void k_mega(MegaArgs a) {
    __shared__ __align__(16) char smem[45056];
    const int wb = blockIdx.x;
    const int tid = threadIdx.x;

    float* ws = a.ws;
    float* pe    = ws + OFF_PE;
    float* rr    = ws + OFF_RR;
    float* ew    = ws + OFF_EW;
    float* beta  = ws + OFF_BETA;
    float* alpha = ws + OFF_ALPHA;
    float* h1    = ws + OFF_H1;
    float* x     = ws + OFF_X;
    float* x2    = ws + OFF_X2;
    float* qkvb  = ws + OFF_QKV;
    float* part  = ws + OFF_PART;
    float* wt    = ws + OFF_WT;
    int* topi   = (int*)(ws + OFF_TOPI);
    int* idxarr = (int*)(ws + OFF_IDX);
    int* lens   = (int*)(ws + OFF_LENS);
    int* csrc   = (int*)(ws + OFF_CSRC);
    int* csrl   = (int*)(ws + OFF_CSRL);
    int* bar    = (int*)(ws + OFF_BAR);   // cnt[16], gen@16, ready@17
    int* gen    = bar + 16;
    int* ready  = bar + 17;
    float* outp = a.outp;

    // ---- init handshake (counters are 0xAA-poisoned before every launch) ----
    if (wb == 0 && tid == 0) {
        for (int i = 0; i < 16; ++i)
            __hip_atomic_store(&bar[i], 0, __ATOMIC_RELAXED, __HIP_MEMORY_SCOPE_AGENT);
        __hip_atomic_store(gen, 0, __ATOMIC_RELAXED, __HIP_MEMORY_SCOPE_AGENT);
        __hip_atomic_store(ready, MAGIC, __ATOMIC_RELEASE, __HIP_MEMORY_SCOPE_AGENT);
    } else if (tid == 0) {
        while (__hip_atomic_load(ready, __ATOMIC_RELAXED, __HIP_MEMORY_SCOPE_AGENT) != MAGIC)
            __builtin_amdgcn_s_sleep(2);
        (void)__hip_atomic_load(ready, __ATOMIC_ACQUIRE, __HIP_MEMORY_SCOPE_AGENT);
    }
    __syncthreads();

    // ================= P0: prep + weight transpose =================
    if (wb == 0) {
        for (int c = tid; c < 144; c += 256) rr[c] = fmaxf(a.Ru[c], 0.f);
        for (int e = tid; e < NE; e += 256) {
            int r = e / NND, cc = e % NND;
            ew[e] = (r == cc) ? 1.0f : a.gs[e];
        }
    } else if (wb <= 8) {
        SPrep* sp = (SPrep*)smem;
        int b = wb - 1;
        int cnt = 0;
        for (int l = tid; l < LMAX; l += 256) {
            int v = a.et[b * LMAX + l];
            cnt += (v != 0);
            int ix = max(v - 1, 0);
            idxarr[b * LMAX + l] = ix;
            sp->sidx[l] = ix;
        }
        sp->red[tid] = cnt;
        __syncthreads();
        for (int st = 128; st > 0; st >>= 1) { if (tid < st) sp->red[tid] += sp->red[tid + st]; __syncthreads(); }
        if (tid == 0) lens[b] = sp->red[0];
        if (tid < NND) {
            int c = 0;
            int* lst = csrl + (size_t)(b * NND + tid) * LMAX;
            for (int l = 0; l < LMAX; ++l)
                if (sp->sidx[l] == tid) { lst[c] = l; ++c; }
            csrc[b * NND + tid] = c;
        }
    } else if (wb <= 72) {
        SPrep* sp = (SPrep*)smem;
        if (tid < 8) sp->sts[tid] = (float)pow(215.0, (double)tid / 7.0);
        __syncthreads();
        int i0 = (wb - 9) * 430;
        for (int i = i0 + tid; i < i0 + 430; i += 256) {
            int s = i & 15; int bl = i >> 4;
            float t = a.etime[bl];
            float sc = t / sp->sts[s & 7];
            float v = (s < 8) ? sinf(sc) : cosf(sc);
            pe[i] = v;
            x[(size_t)bl * DTR + 144 + s] = v;
        }
    } else if (wb < 73 + 256) {
        int idx = wb - 73;
        int mat = idx >> 5, sub = idx & 31;
        const float* src; float* dst; int R, C;
        switch (mat) {
            case 0: src = a.qw[0];  dst = wt + 0;               R = 480;   C = DTR;   break;
            case 1: src = a.ow[0];  dst = wt + 76800;           R = DTR;   C = DTR;   break;
            case 2: src = a.f1w[0]; dst = wt + 102400;          R = NHID2; C = DTR;   break;
            case 3: src = a.f2w[0]; dst = wt + 143360;          R = DTR;   C = NHID2; break;
            case 4: src = a.qw[1];  dst = wt + 184320;          R = 480;   C = DTR;   break;
            case 5: src = a.ow[1];  dst = wt + 184320 + 76800;  R = DTR;   C = DTR;   break;
            case 6: src = a.f1w[1]; dst = wt + 184320 + 102400; R = NHID2; C = DTR;   break;
            default: src = a.f2w[1]; dst = wt + 184320 + 143360; R = DTR;  C = NHID2; break;
        }
        int total = R * C;
        for (int i = sub * 256 + tid; i < total; i += 32 * 256) {
            int r = i / C, c = i - r * C;
            dst[c * R + r] = src[i];
        }
    }
    gridbar(bar, gen, 0);

    // ================= P1: beta =================
    if (wb < LMAX) {
        SBeta* sb = (SBeta*)smem;
        const int t = wb;
        for (int i = tid; i < NPAIR; i += 256) sb->idx[i] = idxarr[i];
        for (int i = tid; i < NND * 16; i += 256) sb->mapw[i] = a.mapw[i];
        if (tid < 144) sb->rr[tid] = rr[tid];
        if (tid < 128) { int b = tid >> 4, s = tid & 15; sb->pe[tid] = pe[((size_t)(b * LMAX + t)) * DPE + s]; }
        if (tid < 32) sb->binc[tid] = a.binc[32 * t + tid];

        float4 pre[4];
        {
            const float4* src = (const float4*)(a.Winc + (size_t)(32 * t) * CW);
#pragma unroll
            for (int i = 0; i < 4; ++i) { int k = tid + i * 256; if (k < CW) pre[i] = src[k]; }
        }
        __syncthreads();

        const int l = tid;
        int nb[NBATCH];
        float4 r4b[NBATCH];
        if (l < LMAX) {
#pragma unroll
            for (int b = 0; b < NBATCH; ++b) {
                nb[b] = sb->idx[b * LMAX + l];
                r4b[b] = *(const float4*)&sb->rr[4 * nb[b]];
            }
        }
        float acc[NBATCH];
#pragma unroll
        for (int b = 0; b < NBATCH; ++b) acc[b] = 0.f;

        int p = 0;
        for (int jc = 0; jc < 8; ++jc) {
            float4* buf = (float4*)&sb->rows[p][0];
#pragma unroll
            for (int i = 0; i < 4; ++i) { int k = tid + i * 256; if (k < CW) buf[k] = pre[i]; }
            __syncthreads();
            if (jc < 7) {
                const float4* src = (const float4*)(a.Winc + (size_t)(32 * t + 4 * (jc + 1)) * CW);
#pragma unroll
                for (int i = 0; i < 4; ++i) { int k = tid + i * 256; if (k < CW) pre[i] = src[k]; }
            }
            if (l < LMAX) {
                if (jc < 4) {
#pragma unroll
                    for (int jj = 0; jj < 4; ++jj) {
                        int j = 4 * jc + jj;
                        float4 w4 = *(const float4*)&sb->rows[p][jj * CW + 4 * l];
#pragma unroll
                        for (int b = 0; b < NBATCH; ++b) {
                            float dv = r4b[b].x * w4.x + r4b[b].y * w4.y + r4b[b].z * w4.z + r4b[b].w * w4.w;
                            acc[b] += sb->mapw[nb[b] * 16 + j] * dv;
                        }
                    }
                } else {
#pragma unroll
                    for (int jj = 0; jj < 4; ++jj) {
                        int j = 4 * jc + jj;
                        float4 w4 = *(const float4*)&sb->rows[p][jj * CW + 4 * l];
#pragma unroll
                        for (int b = 0; b < NBATCH; ++b) {
                            float dv = r4b[b].x * w4.x + r4b[b].y * w4.y + r4b[b].z * w4.z + r4b[b].w * w4.w;
                            acc[b] += sb->pe[(b << 4) + (j - 16)] * dv;
                        }
                    }
                }
            }
            __syncthreads();
            p ^= 1;
        }

        if (l < LMAX) {
#pragma unroll
            for (int b = 0; b < NBATCH; ++b) sb->pair[b * LMAX + l] = acc[b];
        }
        __syncthreads();

        for (int bn = tid; bn < NBATCH * NND; bn += 256) {
            int b = bn / NND, n = bn - b * NND;
            int cnt = csrc[bn];
            const int* lst = csrl + (size_t)bn * LMAX;
            float sum = 0.f;
            for (int i = 0; i < cnt; ++i) sum += sb->pair[b * LMAX + lst[i]];
            float bias = 0.f;
#pragma unroll
            for (int s = 0; s < 16; ++s)
                bias += sb->mapw[n * 16 + s] * sb->binc[s] + sb->pe[(b << 4) + s] * sb->binc[16 + s];
            beta[(size_t)bn * LMAX + t] = (sum + bias) * (1.0f / 32.0f);
        }
    }
    gridbar(bar, gen, 1);

    // ================= P2: top-K (fused meanb) =================
    if (wb < 48) {
        STopk* st = (STopk*)smem;
        int chunk = wb % 6, b = wb / 6;
        int wv = tid >> 6, lane = tid & 63;
        for (int n = wv; n < NND; n += 4) {
            const float* p = beta + (size_t)(b * NND + n) * LMAX;
            float s = 0.f;
            for (int t = lane; t < LMAX; t += 64) s += p[t];
            for (int off = 32; off > 0; off >>= 1) s += __shfl_xor(s, off);
            if (lane == 0) st->sm[n] = s / (float)LMAX;
        }
        __syncthreads();
        for (int e = tid; e < NE; e += 256) st->sv[e] = ew[e] * st->sm[e % NND];
        __syncthreads();
        int e = chunk * 216 + tid;
        if (tid < 216) {
            float v = st->sv[e];
            int rank = 0;
            for (int i = 0; i < NE; ++i) {
                float u = st->sv[i];
                rank += (u > v) || (u == v && i < e);
            }
            if (rank < NK) {
                topi[b * NK + rank] = e;
                alpha[b * NK + rank] = v;
            }
        }
    }
    gridbar(bar, gen, 2);

    // ================= P3: h1 (+dist on block 0) =================
    if (wb < NBATCH * NND) {
        SH1* sh = (SH1*)smem;
        int b = wb / NND, n = wb % NND;
        if (tid == 0) sh->cnt = 0;
        __syncthreads();
        for (int k = tid; k < NK; k += 256) {
            int e = topi[b * NK + k];
            if (e % NND == n) {
                int p = atomicAdd(&sh->cnt, 1);
                sh->lsrc[p] = e / NND;
                sh->lew[p] = ew[e];
            }
        }
        __syncthreads();
        int m = sh->cnt;
        const float* bb = beta + ((size_t)b * NND + n) * LMAX;
        for (int c = tid; c < CW; c += 256) {
            int t = c >> 2, o = c & 3;
            float bt = bb[t];
            int id = idxarr[b * LMAX + t];
            float xv = rr[id * 4 + o];
            float acc = 0.f;
            for (int j = 0; j < m; ++j) {
                float g = bt * sh->lew[j];
                if (g > 0.f && sh->lsrc[j] == id) acc += xv * g;
            }
            h1[((size_t)b * NND + n) * CW + c] = acc;
        }
        if (wb == 0) {
            if (tid < 64) {
                int i = tid / 8, j = tid % 8;
                float d2 = 0.f;
                for (int k = 0; k < NK; ++k) {
                    float d = alpha[i * NK + k] - alpha[j * NK + k];
                    d2 += d * d;
                }
                sh->sd[tid] = (d2 > 0.f) ? sqrtf(d2) : 0.f;
            }
            __syncthreads();
            for (int st = 32; st > 0; st >>= 1) { if (tid < st) sh->sd[tid] += sh->sd[tid + st]; __syncthreads(); }
            if (tid == 0) outp[OUT_DIST] = sh->sd[0] / 64.0f;
        }
    }
    gridbar(bar, gen, 3);

    // ================= P4: h2 -> x =================
    if (wb < NBATCH * NND) {
        SH2* sh = (SH2*)smem;
        int b = wb / NND, n = wb % NND;
        if (tid == 0) sh->cnt = 0;
        __syncthreads();
        for (int k = tid; k < NK; k += 256) {
            int e = topi[b * NK + k];
            if (e % NND == n) {
                int p = atomicAdd(&sh->cnt, 1);
                sh->lsrc[p] = e / NND;
                sh->lal[p] = fmaxf(alpha[b * NK + k], 0.f);
            }
        }
        __syncthreads();
        int m = sh->cnt;
        for (int c = tid; c < CW; c += 256) {
            float acc = 0.f;
            for (int j = 0; j < m; ++j)
                acc += fmaxf(h1[((size_t)b * NND + sh->lsrc[j]) * CW + c], 0.f) * sh->lal[j];
            x[(size_t)(b * LMAX + (c >> 2)) * DTR + 4 * n + (c & 3)] = acc;
        }
    }
    gridbar(bar, gen, 4);

    // ================= transformer layers =================
    for (int layer = 0; layer < 2; ++layer) {
        const float* qkvT = wt + (size_t)layer * 184320;
        const float* outT = qkvT + 76800;
        const float* ff1T = qkvT + 102400;
        const float* ff2T = qkvT + 143360;
        const float* in_x = x;   // layer input
        float* ff_out = (layer == 0) ? x : outp;

        // ---- qkv ----
        {
            SQkv* sq = (SQkv*)smem;
            int m0 = wb * ROWS;
            for (int i = tid; i < ROWS * DTR; i += 256) sq->xs[i] = in_x[(size_t)m0 * DTR + i];
            __syncthreads();
            for (int n = tid; n < 480; n += 256) {
                float acr[ROWS][4];
#pragma unroll
                for (int r = 0; r < ROWS; ++r) { acr[r][0] = acr[r][1] = acr[r][2] = acr[r][3] = 0.f; }
                for (int d = 0; d < DTR; d += 4) {
                    float w0 = qkvT[(size_t)(d + 0) * 480 + n];
                    float w1 = qkvT[(size_t)(d + 1) * 480 + n];
                    float w2 = qkvT[(size_t)(d + 2) * 480 + n];
                    float w3 = qkvT[(size_t)(d + 3) * 480 + n];
#pragma unroll
                    for (int r = 0; r < ROWS; ++r) {
                        acr[r][0] += sq->xs[r * DTR + d] * w0;
                        acr[r][1] += sq->xs[r * DTR + d + 1] * w1;
                        acr[r][2] += sq->xs[r * DTR + d + 2] * w2;
                        acr[r][3] += sq->xs[r * DTR + d + 3] * w3;
                    }
                }
                float bv = a.qb[layer][n];
#pragma unroll
                for (int r = 0; r < ROWS; ++r)
                    qkvb[(size_t)(m0 + r) * 480 + n] = bv + (acr[r][0] + acr[r][1]) + (acr[r][2] + acr[r][3]);
            }
        }
        gridbar(bar, gen, 5 + layer * 4);

        // ---- attn partials ----
        if (wb < 256) {
            SAttn* sa = (SAttn*)smem;
            int kq = wb & 7, bh = wb >> 3;
            int b = bh >> 2, h = bh & 3;
            int k0 = kq * KQLEN;
            int k1 = min(LMAX, k0 + KQLEN);
            int klen = max(k1 - k0, 0);
            for (int i = tid; i < klen * DH; i += 256) {
                int kk = i / DH, d = i - kk * DH;
                size_t base = (size_t)(b * LMAX + k0 + kk) * 480;
                sa->K[i] = qkvb[base + DTR + h * DH + d];
                sa->V[i] = qkvb[base + 2 * DTR + h * DH + d];
            }
            __syncthreads();
            int q = tid;
            if (q < LMAX) {
                float4 qv[10];
                const float4* qr = (const float4*)(qkvb + (size_t)(b * LMAX + q) * 480 + h * DH);
#pragma unroll
                for (int i = 0; i < 10; ++i) qv[i] = qr[i];
                int len = lens[b];
                const float scale = 0.15811388300841898f;
                float m = -INFINITY, l = 0.f;
                float o[DH];
#pragma unroll
                for (int d = 0; d < DH; ++d) o[d] = 0.f;
                int kend = min(k1, len);
                for (int k = k0; k < kend; ++k) {
                    const float4* kr = (const float4*)&sa->K[(k - k0) * DH];
                    float s0 = 0.f, s1 = 0.f, s2 = 0.f, s3 = 0.f;
#pragma unroll
                    for (int i = 0; i < 10; ++i) {
                        float4 kv = kr[i];
                        s0 += qv[i].x * kv.x; s1 += qv[i].y * kv.y;
                        s2 += qv[i].z * kv.z; s3 += qv[i].w * kv.w;
                    }
                    float s = ((s0 + s1) + (s2 + s3)) * scale;
                    float p;
                    if (s <= m) {
                        p = expf(s - m);
                    } else {
                        float c = expf(m - s);
#pragma unroll
                        for (int d = 0; d < DH; ++d) o[d] *= c;
                        l *= c;
                        m = s;
                        p = 1.0f;
                    }
                    l += p;
                    const float* vr = &sa->V[(k - k0) * DH];
#pragma unroll
                    for (int d = 0; d < DH; ++d) o[d] += p * vr[d];
                }
                float* pp = part + ((size_t)(bh * KSPLIT + kq) * LMAX + q) * 42;
#pragma unroll
                for (int d = 0; d < DH; ++d) pp[d] = o[d];
                pp[40] = l;
                pp[41] = m;
            }
        }
        gridbar(bar, gen, 6 + layer * 4);

        // ---- merge + out-proj + residual + LN1 ----
        {
            SProj* sp = (SProj*)smem;
            int m0 = wb * ROWS;
            int g = tid >> 6, lane = tid & 63;
            for (int pr = g; pr < ROWS * NHEADS; pr += 4) {
                int r = pr >> 2, h = pr & 3;
                int row = m0 + r;
                int b = row / LMAX, q = row - b * LMAX;
                const float* pb = part + ((size_t)((b * NHEADS + h) * KSPLIT) * LMAX + q) * 42;
                const size_t st = (size_t)LMAX * 42;
                float ms = -INFINITY;
#pragma unroll
                for (int i = 0; i < KSPLIT; ++i) ms = fmaxf(ms, pb[i * st + 41]);
                float lsum = 0.f, acc = 0.f;
#pragma unroll
                for (int i = 0; i < KSPLIT; ++i) {
                    float w = expf(pb[i * st + 41] - ms);
                    lsum += w * pb[i * st + 40];
                    if (lane < DH) acc += w * pb[i * st + lane];
                }
                if (lane < DH) sp->xs[r * DTR + h * DH + lane] = acc / lsum;
            }
            __syncthreads();
            if (tid < DTR) {
                int n = tid;
                float acr[ROWS][4];
#pragma unroll
                for (int r = 0; r < ROWS; ++r) { acr[r][0] = acr[r][1] = acr[r][2] = acr[r][3] = 0.f; }
                for (int d = 0; d < DTR; d += 4) {
                    float w0 = outT[(size_t)(d + 0) * DTR + n];
                    float w1 = outT[(size_t)(d + 1) * DTR + n];
                    float w2 = outT[(size_t)(d + 2) * DTR + n];
                    float w3 = outT[(size_t)(d + 3) * DTR + n];
#pragma unroll
                    for (int r = 0; r < ROWS; ++r) {
                        acr[r][0] += sp->xs[r * DTR + d] * w0;
                        acr[r][1] += sp->xs[r * DTR + d + 1] * w1;
                        acr[r][2] += sp->xs[r * DTR + d + 2] * w2;
                        acr[r][3] += sp->xs[r * DTR + d + 3] * w3;
                    }
                }
                float bv = a.ob[layer][n];
#pragma unroll
                for (int r = 0; r < ROWS; ++r)
                    sp->ys[r * DTR + n] = bv + (acr[r][0] + acr[r][1]) + (acr[r][2] + acr[r][3])
                                          + in_x[(size_t)(m0 + r) * DTR + n];
            }
            __syncthreads();
            if (g < ROWS)
                wave_ln_row(&sp->ys[g * DTR], lane, a.l1w[layer], a.l1b[layer],
                            x2 + (size_t)(m0 + g) * DTR);
        }
        gridbar(bar, gen, 7 + layer * 4);

        // ---- FF1+relu+FF2+residual+LN2 (+pred epilogue on last layer) ----
        {
            SFf* sf = (SFf*)smem;
            int m0 = wb * ROWS;
            int last = (layer == 1);
            for (int i = tid; i < ROWS * DTR; i += 256) sf->xs[i] = x2[(size_t)m0 * DTR + i];
            __syncthreads();
            {
                int n = tid;
                float acr[ROWS][4];
#pragma unroll
                for (int r = 0; r < ROWS; ++r) { acr[r][0] = acr[r][1] = acr[r][2] = acr[r][3] = 0.f; }
                for (int d = 0; d < DTR; d += 4) {
                    float w0 = ff1T[(size_t)(d + 0) * NHID2 + n];
                    float w1 = ff1T[(size_t)(d + 1) * NHID2 + n];
                    float w2 = ff1T[(size_t)(d + 2) * NHID2 + n];
                    float w3 = ff1T[(size_t)(d + 3) * NHID2 + n];
#pragma unroll
                    for (int r = 0; r < ROWS; ++r) {
                        acr[r][0] += sf->xs[r * DTR + d] * w0;
                        acr[r][1] += sf->xs[r * DTR + d + 1] * w1;
                        acr[r][2] += sf->xs[r * DTR + d + 2] * w2;
                        acr[r][3] += sf->xs[r * DTR + d + 3] * w3;
                    }
                }
                float bv = a.f1b[layer][n];
#pragma unroll
                for (int r = 0; r < ROWS; ++r)
                    sf->hs[r * NHID2 + n] = fmaxf(bv + (acr[r][0] + acr[r][1]) + (acr[r][2] + acr[r][3]), 0.f);
            }
            __syncthreads();
            if (tid < DTR) {
                int n = tid;
                float acr[ROWS][4];
#pragma unroll
                for (int r = 0; r < ROWS; ++r) { acr[r][0] = acr[r][1] = acr[r][2] = acr[r][3] = 0.f; }
                for (int d = 0; d < NHID2; d += 4) {
                    float w0 = ff2T[(size_t)(d + 0) * DTR + n];
                    float w1 = ff2T[(size_t)(d + 1) * DTR + n];
                    float w2 = ff2T[(size_t)(d + 2) * DTR + n];
                    float w3 = ff2T[(size_t)(d + 3) * DTR + n];
#pragma unroll
                    for (int r = 0; r < ROWS; ++r) {
                        acr[r][0] += sf->hs[r * NHID2 + d] * w0;
                        acr[r][1] += sf->hs[r * NHID2 + d + 1] * w1;
                        acr[r][2] += sf->hs[r * NHID2 + d + 2] * w2;
                        acr[r][3] += sf->hs[r * NHID2 + d + 3] * w3;
                    }
                }
                float bv = a.f2b[layer][n];
#pragma unroll
                for (int r = 0; r < ROWS; ++r)
                    sf->zs[r * DTR + n] = bv + (acr[r][0] + acr[r][1]) + (acr[r][2] + acr[r][3]) + sf->xs[r * DTR + n];
            }
            __syncthreads();
            int wid = tid >> 6, lane = tid & 63;
            if (!last) {
                if (wid < ROWS)
                    wave_ln_row(&sf->zs[wid * DTR], lane, a.l2w[layer], a.l2b[layer],
                                ff_out + (size_t)(m0 + wid) * DTR);
            } else {
                if (wid < ROWS)
                    wave_ln_row(&sf->zs[wid * DTR], lane, a.l2w[layer], a.l2b[layer],
                                &sf->fin[wid * DTR]);
                __syncthreads();
                for (int i = tid; i < ROWS * DTR; i += 256) ff_out[(size_t)m0 * DTR + i] = sf->fin[i];
                int row = m0 + wid;
                int b = row / LMAX, l = row - b * LMAX;
                float np = (l < lens[b]) ? 1.f : 0.f;
                if (lane < 37) {
                    const float* w = (lane < 36) ? (a.wtype + lane * DTR) : a.wtime;
                    const float* fr = &sf->fin[wid * DTR];
                    float acc = 0.f;
#pragma unroll 8
                    for (int d = 0; d < DTR; d += 4) {
                        float4 w4 = *(const float4*)(w + d);
                        acc += fr[d] * w4.x + fr[d + 1] * w4.y + fr[d + 2] * w4.z + fr[d + 3] * w4.w;
                    }
                    acc *= np;
                    if (lane < 36) ff_out[OUT_TYPE + (size_t)row * NND + lane] = acc;
                    else ff_out[OUT_TIME + row] = acc;
                }
            }
        }
        if (layer == 0) gridbar(bar, gen, 8);
    }
}

// ---------------------------------------------------------------- launch
extern "C" void kernel_launch(void* const* d_in, const int* in_sizes, int n_in,
                              void* d_out, int out_size, void* d_ws, size_t ws_size,
                              hipStream_t stream) {
    MegaArgs a;
    a.et    = (const int*)d_in[0];
    a.etime = (const float*)d_in[1];
    a.Ru    = (const float*)d_in[2];
    a.gs    = (const float*)d_in[3];
    a.Winc  = (const float*)d_in[4];
    a.binc  = (const float*)d_in[5];
    a.mapw  = (const float*)d_in[6];
    a.wtime = (const float*)d_in[7];
    a.wtype = (const float*)d_in[8];
    for (int layer = 0; layer < 2; ++layer) {
        int base = 9 + layer * 12;
        a.qw[layer]  = (const float*)d_in[base + 0];
        a.qb[layer]  = (const float*)d_in[base + 1];
        a.ow[layer]  = (const float*)d_in[base + 2];
        a.ob[layer]  = (const float*)d_in[base + 3];
        a.f1w[layer] = (const float*)d_in[base + 4];
        a.f1b[layer] = (const float*)d_in[base + 5];
        a.f2w[layer] = (const float*)d_in[base + 6];
        a.f2b[layer] = (const float*)d_in[base + 7];
        a.l1w[layer] = (const float*)d_in[base + 8];
        a.l1b[layer] = (const float*)d_in[base + 9];
        a.l2w[layer] = (const float*)d_in[base + 10];
        a.l2b[layer] = (const float*)d_in[base + 11];
    }
    a.ws   = (float*)d_ws;
    a.outp = (float*)d_out;

    k_mega<<<NBLK, 256, 0, stream>>>(a);
}

// Round 13
// 400.848 us; speedup vs baseline: 1.8724x; 1.8724x over previous
//
#include <hip/hip_runtime.h>
#include <math.h>

#define NBATCH 8
#define LMAX   215
#define NND    36
#define NE     1296
#define NK     648
#define CW     860      // C = LMAX*4
#define DPE    16
#define DTR    160
#define NHEADS 4
#define DH     40
#define NHID2  256
#define NPAIR  (NBATCH*LMAX)   // 1720
#define KSPLIT 8
#define KQLEN  27              // ceil(215/8)
#define ROWS   4               // rows per GEMM tile

// output layout (floats)
#define OUT_TYPE (NBATCH*LMAX*DTR)              // 275200
#define OUT_TIME (OUT_TYPE + NBATCH*LMAX*NND)   // 337120
#define OUT_DIST (OUT_TIME + NBATCH*LMAX)       // 338840

// workspace layout (float offsets)
#define OFF_PE    0
#define OFF_RR    (OFF_PE + NBATCH*LMAX*DPE)
#define OFF_EW    (OFF_RR + 144)
#define OFF_BETA  (OFF_EW + NE)
#define OFF_ALPHA (OFF_BETA + NBATCH*NND*LMAX)
#define OFF_H1    (OFF_ALPHA + NBATCH*NK)
#define OFF_X     (OFF_H1 + NBATCH*NND*CW)
#define OFF_QKV   (OFF_X + NBATCH*LMAX*DTR)
#define OFF_TOPI  (OFF_QKV + NBATCH*LMAX*480)
#define OFF_IDX   (OFF_TOPI + NBATCH*NK)
#define OFF_LENS  (OFF_IDX + NBATCH*LMAX)
#define OFF_PART  (OFF_LENS + NBATCH)
#define OFF_CSRC  (OFF_PART + 32*KSPLIT*LMAX*42)
#define OFF_CSRL  (OFF_CSRC + NBATCH*NND)
#define OFF_WT    (OFF_CSRL + NBATCH*NND*LMAX)
// per layer: qkvT @0, outT @76800, ff1T @102400, ff2T @143360 ; stride 184320

// ---------------------------------------------------------------- prep + weight transpose (329 blocks)
__global__ __launch_bounds__(256) void k_prep(
        const int* __restrict__ et, const float* __restrict__ etime,
        const float* __restrict__ Ru, const float* __restrict__ gs,
        const float* __restrict__ q0, const float* __restrict__ o0,
        const float* __restrict__ f10, const float* __restrict__ f20,
        const float* __restrict__ q1, const float* __restrict__ o1,
        const float* __restrict__ f11, const float* __restrict__ f21,
        float* pe, float* rr, float* ew, int* idxarr, int* lens,
        int* csr_cnt, int* csr_list, float* __restrict__ x, float* __restrict__ wt) {
    int blk = blockIdx.x, tid = threadIdx.x;
    if (blk == 0) {
        for (int c = tid; c < 144; c += 256) rr[c] = fmaxf(Ru[c], 0.f);
        for (int e = tid; e < NE; e += 256) {
            int r = e / NND, cc = e % NND;
            ew[e] = (r == cc) ? 1.0f : gs[e];
        }
    } else if (blk <= 8) {
        int b = blk - 1;
        __shared__ int red[256];
        __shared__ int sidx[LMAX];
        int cnt = 0;
        for (int l = tid; l < LMAX; l += 256) {
            int v = et[b * LMAX + l];
            cnt += (v != 0);
            int ix = max(v - 1, 0);
            idxarr[b * LMAX + l] = ix;
            sidx[l] = ix;
        }
        red[tid] = cnt;
        __syncthreads();
        for (int st = 128; st > 0; st >>= 1) { if (tid < st) red[tid] += red[tid + st]; __syncthreads(); }
        if (tid == 0) lens[b] = red[0];
        if (tid < NND) {
            int c = 0;
            int* lst = csr_list + (size_t)(b * NND + tid) * LMAX;
            for (int l = 0; l < LMAX; ++l)
                if (sidx[l] == tid) { lst[c] = l; ++c; }
            csr_cnt[b * NND + tid] = c;
        }
    } else if (blk <= 72) {
        __shared__ float sts[8];
        if (tid < 8) sts[tid] = (float)pow(215.0, (double)tid / 7.0);
        __syncthreads();
        int i0 = (blk - 9) * 430;
        for (int i = i0 + tid; i < i0 + 430; i += 256) {
            int s = i & 15; int bl = i >> 4;
            float t = etime[bl];
            float sc = t / sts[s & 7];
            float v = (s < 8) ? sinf(sc) : cosf(sc);
            pe[i] = v;
            x[(size_t)bl * DTR + 144 + s] = v;
        }
    } else {
        int idx = blk - 73;                 // 0..255
        int mat = idx >> 5, sub = idx & 31;
        const float* src; float* dst; int R, C;
        switch (mat) {
            case 0: src = q0;  dst = wt + 0;               R = 480;   C = DTR;   break;
            case 1: src = o0;  dst = wt + 76800;           R = DTR;   C = DTR;   break;
            case 2: src = f10; dst = wt + 102400;          R = NHID2; C = DTR;   break;
            case 3: src = f20; dst = wt + 143360;          R = DTR;   C = NHID2; break;
            case 4: src = q1;  dst = wt + 184320;          R = 480;   C = DTR;   break;
            case 5: src = o1;  dst = wt + 184320 + 76800;  R = DTR;   C = DTR;   break;
            case 6: src = f11; dst = wt + 184320 + 102400; R = NHID2; C = DTR;   break;
            default: src = f21; dst = wt + 184320 + 143360; R = DTR;  C = NHID2; break;
        }
        int total = R * C;
        for (int i = sub * 256 + tid; i < total; i += 32 * 256) {
            int r = i / C, c = i - r * C;
            dst[c * R + r] = src[i];
        }
    }
}

// ---------------------------------------------------------------- beta (thread-owns-l, b-loop in regs, CSR reduce)
__global__ __launch_bounds__(256) void k_beta(
        const float* __restrict__ Winc, const float* __restrict__ binc,
        const float* __restrict__ mapw, const float* __restrict__ pe,
        const float* __restrict__ rr, const int* __restrict__ idxarr,
        const int* __restrict__ csr_cnt, const int* __restrict__ csr_list,
        float* __restrict__ beta) {
    const int t = blockIdx.x;        // 0..214
    const int tid = threadIdx.x;     // 256

    __shared__ float s_rows[2][4 * CW];
    __shared__ float s_pair[NBATCH * LMAX];
    __shared__ int   s_idx[NPAIR];
    __shared__ float s_mapw[NND * 16];
    __shared__ float s_rr[144];
    __shared__ float s_pe[NBATCH * 16];
    __shared__ float s_binc[32];

    for (int i = tid; i < NPAIR; i += 256) s_idx[i] = idxarr[i];
    for (int i = tid; i < NND * 16; i += 256) s_mapw[i] = mapw[i];
    if (tid < 144) s_rr[tid] = rr[tid];
    if (tid < 128) { int b = tid >> 4, s = tid & 15; s_pe[tid] = pe[((size_t)(b * LMAX + t)) * DPE + s]; }
    if (tid < 32) s_binc[tid] = binc[32 * t + tid];

    float4 pre[4];
    {
        const float4* src = (const float4*)(Winc + (size_t)(32 * t) * CW);
#pragma unroll
        for (int i = 0; i < 4; ++i) { int k = tid + i * 256; if (k < CW) pre[i] = src[k]; }
    }
    __syncthreads();

    const int l = tid;
    int nb[NBATCH];
    float4 r4b[NBATCH];
    if (l < LMAX) {
#pragma unroll
        for (int b = 0; b < NBATCH; ++b) {
            nb[b] = s_idx[b * LMAX + l];
            r4b[b] = *(const float4*)&s_rr[4 * nb[b]];
        }
    }
    float acc[NBATCH];
#pragma unroll
    for (int b = 0; b < NBATCH; ++b) acc[b] = 0.f;

    int p = 0;
    for (int jc = 0; jc < 8; ++jc) {
        float4* buf = (float4*)&s_rows[p][0];
#pragma unroll
        for (int i = 0; i < 4; ++i) { int k = tid + i * 256; if (k < CW) buf[k] = pre[i]; }
        __syncthreads();
        if (jc < 7) {
            const float4* src = (const float4*)(Winc + (size_t)(32 * t + 4 * (jc + 1)) * CW);
#pragma unroll
            for (int i = 0; i < 4; ++i) { int k = tid + i * 256; if (k < CW) pre[i] = src[k]; }
        }
        if (l < LMAX) {
            if (jc < 4) {
#pragma unroll
                for (int jj = 0; jj < 4; ++jj) {
                    int j = 4 * jc + jj;
                    float4 w4 = *(const float4*)&s_rows[p][jj * CW + 4 * l];
#pragma unroll
                    for (int b = 0; b < NBATCH; ++b) {
                        float dv = r4b[b].x * w4.x + r4b[b].y * w4.y + r4b[b].z * w4.z + r4b[b].w * w4.w;
                        acc[b] += s_mapw[nb[b] * 16 + j] * dv;
                    }
                }
            } else {
#pragma unroll
                for (int jj = 0; jj < 4; ++jj) {
                    int j = 4 * jc + jj;
                    float4 w4 = *(const float4*)&s_rows[p][jj * CW + 4 * l];
#pragma unroll
                    for (int b = 0; b < NBATCH; ++b) {
                        float dv = r4b[b].x * w4.x + r4b[b].y * w4.y + r4b[b].z * w4.z + r4b[b].w * w4.w;
                        acc[b] += s_pe[(b << 4) + (j - 16)] * dv;
                    }
                }
            }
        }
        __syncthreads();
        p ^= 1;
    }

    if (l < LMAX) {
#pragma unroll
        for (int b = 0; b < NBATCH; ++b) s_pair[b * LMAX + l] = acc[b];
    }
    __syncthreads();

    for (int bn = tid; bn < NBATCH * NND; bn += 256) {
        int b = bn / NND, n = bn - b * NND;
        int cnt = csr_cnt[bn];
        const int* lst = csr_list + (size_t)bn * LMAX;
        float sum = 0.f;
        for (int i = 0; i < cnt; ++i) sum += s_pair[b * LMAX + lst[i]];
        float bias = 0.f;
#pragma unroll
        for (int s = 0; s < 16; ++s)
            bias += s_mapw[n * 16 + s] * s_binc[s] + s_pe[(b << 4) + s] * s_binc[16 + s];
        beta[(size_t)bn * LMAX + t] = (sum + bias) * (1.0f / 32.0f);
    }
}

// ---------------------------------------------------------------- top-K with fused meanb (bitwise-identical reduce)
__global__ __launch_bounds__(256) void k_topk(const float* __restrict__ ew,
                                              const float* __restrict__ beta,
                                              int* __restrict__ topi, float* __restrict__ alpha) {
    int chunk = blockIdx.x;    // 0..5
    int b = blockIdx.y;        // 0..7
    int tid = threadIdx.x;     // 256
    __shared__ float sv[NE];
    __shared__ float sm[NND];
    int wv = tid >> 6, lane = tid & 63;
    for (int n = wv; n < NND; n += 4) {
        const float* p = beta + (size_t)(b * NND + n) * LMAX;
        float s = 0.f;
        for (int t = lane; t < LMAX; t += 64) s += p[t];
        for (int off = 32; off > 0; off >>= 1) s += __shfl_xor(s, off);
        if (lane == 0) sm[n] = s / (float)LMAX;
    }
    __syncthreads();
    for (int e = tid; e < NE; e += 256) sv[e] = ew[e] * sm[e % NND];
    __syncthreads();
    int e = chunk * 216 + tid;
    if (tid < 216) {
        float v = sv[e];
        int rank = 0;
        for (int i = 0; i < NE; ++i) {
            float u = sv[i];
            rank += (u > v) || (u == v && i < e);
        }
        if (rank < NK) {
            topi[b * NK + rank] = e;
            alpha[b * NK + rank] = v;
        }
    }
}

// ---------------------------------------------------------------- message passing layer 1 (+ fused distance in block 0)
__global__ void k_h1(const int* __restrict__ topi, const float* __restrict__ ew,
                     const float* __restrict__ beta, const int* __restrict__ idxarr,
                     const float* __restrict__ rr, const float* __restrict__ alpha,
                     float* h1, float* __restrict__ outd) {
    int b = blockIdx.x / NND, n = blockIdx.x % NND;
    __shared__ int cnt;
    __shared__ int lsrc[40];
    __shared__ float lew[40];
    int tid = threadIdx.x;
    if (tid == 0) cnt = 0;
    __syncthreads();
    for (int k = tid; k < NK; k += 256) {
        int e = topi[b * NK + k];
        if (e % NND == n) {
            int p = atomicAdd(&cnt, 1);
            lsrc[p] = e / NND;
            lew[p] = ew[e];
        }
    }
    __syncthreads();
    int m = cnt;
    const float* bb = beta + ((size_t)b * NND + n) * LMAX;
    for (int c = tid; c < CW; c += 256) {
        int t = c >> 2, o = c & 3;
        float bt = bb[t];
        int id = idxarr[b * LMAX + t];
        float xv = rr[id * 4 + o];
        float acc = 0.f;
        for (int j = 0; j < m; ++j) {
            float g = bt * lew[j];
            if (g > 0.f && lsrc[j] == id) acc += xv * g;
        }
        h1[((size_t)b * NND + n) * CW + c] = acc;
    }
    if (blockIdx.x == 0) {
        __shared__ float sd[64];
        if (tid < 64) {
            int i = tid / 8, j = tid % 8;
            float d2 = 0.f;
            for (int k = 0; k < NK; ++k) {
                float d = alpha[i * NK + k] - alpha[j * NK + k];
                d2 += d * d;
            }
            sd[tid] = (d2 > 0.f) ? sqrtf(d2) : 0.f;
        }
        __syncthreads();
        for (int st = 32; st > 0; st >>= 1) { if (tid < st) sd[tid] += sd[tid + st]; __syncthreads(); }
        if (tid == 0) *outd = sd[0] / 64.0f;
    }
}

// ---------------------------------------------------------------- message passing layer 2 -> writes x directly
__global__ void k_h2(const int* __restrict__ topi, const float* __restrict__ alpha,
                     const float* __restrict__ h1, float* __restrict__ x) {
    int b = blockIdx.x / NND, n = blockIdx.x % NND;
    __shared__ int cnt;
    __shared__ int lsrc[40];
    __shared__ float lal[40];
    int tid = threadIdx.x;
    if (tid == 0) cnt = 0;
    __syncthreads();
    for (int k = tid; k < NK; k += 256) {
        int e = topi[b * NK + k];
        if (e % NND == n) {
            int p = atomicAdd(&cnt, 1);
            lsrc[p] = e / NND;
            lal[p] = fmaxf(alpha[b * NK + k], 0.f);
        }
    }
    __syncthreads();
    int m = cnt;
    for (int c = tid; c < CW; c += 256) {
        float acc = 0.f;
        for (int j = 0; j < m; ++j)
            acc += fmaxf(h1[((size_t)b * NND + lsrc[j]) * CW + c], 0.f) * lal[j];
        x[(size_t)(b * LMAX + (c >> 2)) * DTR + 4 * n + (c & 3)] = acc;
    }
}

// ---------------------------------------------------------------- qkv GEMM: 4 rows/block, transposed W, coalesced
__global__ __launch_bounds__(256) void k_qkv(const float* __restrict__ X, const float* __restrict__ WT,
                                             const float* __restrict__ bias, float* __restrict__ Y) {
    int m0 = blockIdx.x * ROWS;
    int tid = threadIdx.x;
    __shared__ float xs[ROWS * DTR];
    for (int i = tid; i < ROWS * DTR; i += 256) xs[i] = X[(size_t)m0 * DTR + i];
    __syncthreads();
    for (int n = tid; n < 480; n += 256) {
        float a[ROWS][4];
#pragma unroll
        for (int r = 0; r < ROWS; ++r) { a[r][0] = a[r][1] = a[r][2] = a[r][3] = 0.f; }
        for (int d = 0; d < DTR; d += 4) {
            float w0 = WT[(size_t)(d + 0) * 480 + n];
            float w1 = WT[(size_t)(d + 1) * 480 + n];
            float w2 = WT[(size_t)(d + 2) * 480 + n];
            float w3 = WT[(size_t)(d + 3) * 480 + n];
#pragma unroll
            for (int r = 0; r < ROWS; ++r) {
                a[r][0] += xs[r * DTR + d] * w0;
                a[r][1] += xs[r * DTR + d + 1] * w1;
                a[r][2] += xs[r * DTR + d + 2] * w2;
                a[r][3] += xs[r * DTR + d + 3] * w3;
            }
        }
        float bv = bias[n];
#pragma unroll
        for (int r = 0; r < ROWS; ++r)
            Y[(size_t)(m0 + r) * 480 + n] = bv + (a[r][0] + a[r][1]) + (a[r][2] + a[r][3]);
    }
}

// ---------------------------------------------------------------- attention partials (flash 8-way k-split)
__global__ __launch_bounds__(256) void k_attn_part(const float* __restrict__ qkv,
                                                   const int* __restrict__ lens,
                                                   float* __restrict__ part) {
    int kq = blockIdx.x;           // 0..7
    int bh = blockIdx.y;           // 0..31
    int b = bh >> 2, h = bh & 3;
    int tid = threadIdx.x;
    int k0 = kq * KQLEN;
    int k1 = min(LMAX, k0 + KQLEN);
    int klen = max(k1 - k0, 0);
    __shared__ float sK[KQLEN * DH];
    __shared__ float sV[KQLEN * DH];
    for (int i = tid; i < klen * DH; i += 256) {
        int kk = i / DH, d = i - kk * DH;
        size_t base = (size_t)(b * LMAX + k0 + kk) * 480;
        sK[i] = qkv[base + DTR + h * DH + d];
        sV[i] = qkv[base + 2 * DTR + h * DH + d];
    }
    __syncthreads();
    int q = tid;
    if (q >= LMAX) return;
    float4 qv[10];
    const float4* qr = (const float4*)(qkv + (size_t)(b * LMAX + q) * 480 + h * DH);
#pragma unroll
    for (int i = 0; i < 10; ++i) qv[i] = qr[i];
    int len = lens[b];
    const float scale = 0.15811388300841898f;
    float m = -INFINITY, l = 0.f;
    float o[DH];
#pragma unroll
    for (int d = 0; d < DH; ++d) o[d] = 0.f;
    int kend = min(k1, len);
    for (int k = k0; k < kend; ++k) {
        const float4* kr = (const float4*)&sK[(k - k0) * DH];
        float s0 = 0.f, s1 = 0.f, s2 = 0.f, s3 = 0.f;
#pragma unroll
        for (int i = 0; i < 10; ++i) {
            float4 kv = kr[i];
            s0 += qv[i].x * kv.x; s1 += qv[i].y * kv.y;
            s2 += qv[i].z * kv.z; s3 += qv[i].w * kv.w;
        }
        float s = ((s0 + s1) + (s2 + s3)) * scale;
        float p;
        if (s <= m) {
            p = expf(s - m);
        } else {
            float c = expf(m - s);
#pragma unroll
            for (int d = 0; d < DH; ++d) o[d] *= c;
            l *= c;
            m = s;
            p = 1.0f;
        }
        l += p;
        const float* vr = &sV[(k - k0) * DH];
#pragma unroll
        for (int d = 0; d < DH; ++d) o[d] += p * vr[d];
    }
    float* pp = part + ((size_t)(bh * KSPLIT + kq) * LMAX + q) * 42;
#pragma unroll
    for (int d = 0; d < DH; ++d) pp[d] = o[d];
    pp[40] = l;
    pp[41] = m;
}

// ---------------------------------------------------------------- device LN helper
__device__ __forceinline__ void wave_ln_row(const float* row, int lane,
                                            const float* lnw, const float* lnb, float* dst) {
    float s = 0.f;
    for (int d = lane; d < DTR; d += 64) s += row[d];
    for (int off = 32; off > 0; off >>= 1) s += __shfl_xor(s, off);
    float mu = s / (float)DTR;
    float v = 0.f;
    for (int d = lane; d < DTR; d += 64) { float dd = row[d] - mu; v += dd * dd; }
    for (int off = 32; off > 0; off >>= 1) v += __shfl_xor(v, off);
    float rs = rsqrtf(v / (float)DTR + 1e-5f);
    for (int d = lane; d < DTR; d += 64)
        dst[d] = (row[d] - mu) * rs * lnw[d] + lnb[d];
}

// ---------------------------------------------------------------- merge + out-proj + LN1 + FF1 + FF2 + LN2 (+pred)
__global__ __launch_bounds__(256) void k_projffln(
        const float* __restrict__ part, const float* __restrict__ xres,
        const float* __restrict__ WT, const float* __restrict__ bias,
        const float* __restrict__ ln1w, const float* __restrict__ ln1b,
        const float* __restrict__ W1T, const float* __restrict__ b1,
        const float* __restrict__ W2T, const float* __restrict__ b2,
        const float* __restrict__ ln2w, const float* __restrict__ ln2b,
        float* __restrict__ out, int last,
        const float* __restrict__ wty, const float* __restrict__ wti,
        const int* __restrict__ lens) {
    int m0 = blockIdx.x * ROWS;
    int tid = threadIdx.x;
    __shared__ float xs[ROWS * DTR];    // ctx, later zs (FF2 out)
    __shared__ float ys[ROWS * DTR];    // proj+res, later fin
    __shared__ float x2s[ROWS * DTR];   // LN1 out (ffln input)
    __shared__ float hs[ROWS * NHID2];  // FF1 out
    int g = tid >> 6, lane = tid & 63;

    // ---- merge 8 k-split partials -> ctx rows in LDS ----
    for (int pr = g; pr < ROWS * NHEADS; pr += 4) {
        int r = pr >> 2, h = pr & 3;
        int row = m0 + r;
        int b = row / LMAX, q = row - b * LMAX;
        const float* pb = part + ((size_t)((b * NHEADS + h) * KSPLIT) * LMAX + q) * 42;
        const size_t st = (size_t)LMAX * 42;
        float ms = -INFINITY;
#pragma unroll
        for (int i = 0; i < KSPLIT; ++i) ms = fmaxf(ms, pb[i * st + 41]);
        float lsum = 0.f, acc = 0.f;
#pragma unroll
        for (int i = 0; i < KSPLIT; ++i) {
            float w = expf(pb[i * st + 41] - ms);
            lsum += w * pb[i * st + 40];
            if (lane < DH) acc += w * pb[i * st + lane];
        }
        if (lane < DH) xs[r * DTR + h * DH + lane] = acc / lsum;
    }
    __syncthreads();

    // ---- out-proj + residual ----
    if (tid < DTR) {
        int n = tid;
        float a[ROWS][4];
#pragma unroll
        for (int r = 0; r < ROWS; ++r) { a[r][0] = a[r][1] = a[r][2] = a[r][3] = 0.f; }
        for (int d = 0; d < DTR; d += 4) {
            float w0 = WT[(size_t)(d + 0) * DTR + n];
            float w1 = WT[(size_t)(d + 1) * DTR + n];
            float w2 = WT[(size_t)(d + 2) * DTR + n];
            float w3 = WT[(size_t)(d + 3) * DTR + n];
#pragma unroll
            for (int r = 0; r < ROWS; ++r) {
                a[r][0] += xs[r * DTR + d] * w0;
                a[r][1] += xs[r * DTR + d + 1] * w1;
                a[r][2] += xs[r * DTR + d + 2] * w2;
                a[r][3] += xs[r * DTR + d + 3] * w3;
            }
        }
        float bv = bias[n];
#pragma unroll
        for (int r = 0; r < ROWS; ++r)
            ys[r * DTR + n] = bv + (a[r][0] + a[r][1]) + (a[r][2] + a[r][3])
                              + xres[(size_t)(m0 + r) * DTR + n];
    }
    __syncthreads();

    // ---- LN1 -> x2s (stays in LDS) ----
    if (g < ROWS)
        wave_ln_row(&ys[g * DTR], lane, ln1w, ln1b, &x2s[g * DTR]);
    __syncthreads();

    // ---- FF1 + relu ----
    {
        int n = tid;   // all 256 active
        float a[ROWS][4];
#pragma unroll
        for (int r = 0; r < ROWS; ++r) { a[r][0] = a[r][1] = a[r][2] = a[r][3] = 0.f; }
        for (int d = 0; d < DTR; d += 4) {
            float w0 = W1T[(size_t)(d + 0) * NHID2 + n];
            float w1 = W1T[(size_t)(d + 1) * NHID2 + n];
            float w2 = W1T[(size_t)(d + 2) * NHID2 + n];
            float w3 = W1T[(size_t)(d + 3) * NHID2 + n];
#pragma unroll
            for (int r = 0; r < ROWS; ++r) {
                a[r][0] += x2s[r * DTR + d] * w0;
                a[r][1] += x2s[r * DTR + d + 1] * w1;
                a[r][2] += x2s[r * DTR + d + 2] * w2;
                a[r][3] += x2s[r * DTR + d + 3] * w3;
            }
        }
        float bv = b1[n];
#pragma unroll
        for (int r = 0; r < ROWS; ++r)
            hs[r * NHID2 + n] = fmaxf(bv + (a[r][0] + a[r][1]) + (a[r][2] + a[r][3]), 0.f);
    }
    __syncthreads();

    // ---- FF2 + residual -> xs (reuse) ----
    if (tid < DTR) {
        int n = tid;
        float a[ROWS][4];
#pragma unroll
        for (int r = 0; r < ROWS; ++r) { a[r][0] = a[r][1] = a[r][2] = a[r][3] = 0.f; }
        for (int d = 0; d < NHID2; d += 4) {
            float w0 = W2T[(size_t)(d + 0) * DTR + n];
            float w1 = W2T[(size_t)(d + 1) * DTR + n];
            float w2 = W2T[(size_t)(d + 2) * DTR + n];
            float w3 = W2T[(size_t)(d + 3) * DTR + n];
#pragma unroll
            for (int r = 0; r < ROWS; ++r) {
                a[r][0] += hs[r * NHID2 + d] * w0;
                a[r][1] += hs[r * NHID2 + d + 1] * w1;
                a[r][2] += hs[r * NHID2 + d + 2] * w2;
                a[r][3] += hs[r * NHID2 + d + 3] * w3;
            }
        }
        float bv = b2[n];
#pragma unroll
        for (int r = 0; r < ROWS; ++r)
            xs[r * DTR + n] = bv + (a[r][0] + a[r][1]) + (a[r][2] + a[r][3]) + x2s[r * DTR + n];
    }
    __syncthreads();

    // ---- LN2 -> output (+ preds on last layer) ----
    if (!last) {
        if (g < ROWS)
            wave_ln_row(&xs[g * DTR], lane, ln2w, ln2b, out + (size_t)(m0 + g) * DTR);
        return;
    }
    if (g < ROWS)
        wave_ln_row(&xs[g * DTR], lane, ln2w, ln2b, &ys[g * DTR]);   // ys = fin
    __syncthreads();
    for (int i = tid; i < ROWS * DTR; i += 256) out[(size_t)m0 * DTR + i] = ys[i];
    {
        int row = m0 + g;
        int b = row / LMAX, l = row - b * LMAX;
        float np = (l < lens[b]) ? 1.f : 0.f;
        if (lane < 37) {
            const float* w = (lane < 36) ? (wty + lane * DTR) : wti;
            const float* fr = &ys[g * DTR];
            float acc = 0.f;
#pragma unroll 8
            for (int d = 0; d < DTR; d += 4) {
                float4 w4 = *(const float4*)(w + d);
                acc += fr[d] * w4.x + fr[d + 1] * w4.y + fr[d + 2] * w4.z + fr[d + 3] * w4.w;
            }
            acc *= np;
            if (lane < 36) out[OUT_TYPE + (size_t)row * NND + lane] = acc;
            else out[OUT_TIME + row] = acc;
        }
    }
}

// ---------------------------------------------------------------- launch
extern "C" void kernel_launch(void* const* d_in, const int* in_sizes, int n_in,
                              void* d_out, int out_size, void* d_ws, size_t ws_size,
                              hipStream_t stream) {
    const int* et      = (const int*)d_in[0];
    const float* etime = (const float*)d_in[1];
    const float* Ru    = (const float*)d_in[2];
    const float* gs    = (const float*)d_in[3];
    const float* Winc  = (const float*)d_in[4];
    const float* binc  = (const float*)d_in[5];
    const float* mapw  = (const float*)d_in[6];
    const float* wtime = (const float*)d_in[7];
    const float* wtype = (const float*)d_in[8];

    float* ws   = (float*)d_ws;
    float* pe   = ws + OFF_PE;
    float* rr   = ws + OFF_RR;
    float* ew   = ws + OFF_EW;
    float* beta = ws + OFF_BETA;
    float* alpha= ws + OFF_ALPHA;
    float* h1   = ws + OFF_H1;
    float* x    = ws + OFF_X;
    float* qkvb = ws + OFF_QKV;
    float* part = ws + OFF_PART;
    float* wt   = ws + OFF_WT;
    int* topi   = (int*)(ws + OFF_TOPI);
    int* idxarr = (int*)(ws + OFF_IDX);
    int* lens   = (int*)(ws + OFF_LENS);
    int* csrc   = (int*)(ws + OFF_CSRC);
    int* csrl   = (int*)(ws + OFF_CSRL);
    float* outp = (float*)d_out;

    k_prep<<<329, 256, 0, stream>>>(et, etime, Ru, gs,
        (const float*)d_in[9],  (const float*)d_in[11], (const float*)d_in[13], (const float*)d_in[15],
        (const float*)d_in[21], (const float*)d_in[23], (const float*)d_in[25], (const float*)d_in[27],
        pe, rr, ew, idxarr, lens, csrc, csrl, x, wt);
    k_beta<<<LMAX, 256, 0, stream>>>(Winc, binc, mapw, pe, rr, idxarr, csrc, csrl, beta);
    k_topk<<<dim3(6, NBATCH), 256, 0, stream>>>(ew, beta, topi, alpha);
    k_h1<<<NBATCH * NND, 256, 0, stream>>>(topi, ew, beta, idxarr, rr, alpha, h1, outp + OUT_DIST);
    k_h2<<<NBATCH * NND, 256, 0, stream>>>(topi, alpha, h1, x);

    const int MB4 = NPAIR / ROWS;  // 430 four-row tiles
    for (int layer = 0; layer < 2; ++layer) {
        int base = 9 + layer * 12;
        const float* qkv_b = (const float*)d_in[base + 1];
        const float* out_b = (const float*)d_in[base + 3];
        const float* ff1_b = (const float*)d_in[base + 5];
        const float* ff2_b = (const float*)d_in[base + 7];
        const float* ln1_w = (const float*)d_in[base + 8];
        const float* ln1_b = (const float*)d_in[base + 9];
        const float* ln2_w = (const float*)d_in[base + 10];
        const float* ln2_b = (const float*)d_in[base + 11];
        const float* qkvT = wt + (size_t)layer * 184320;
        const float* outT = qkvT + 76800;
        const float* ff1T = qkvT + 102400;
        const float* ff2T = qkvT + 143360;

        k_qkv<<<MB4, 256, 0, stream>>>(x, qkvT, qkv_b, qkvb);
        k_attn_part<<<dim3(KSPLIT, NBATCH * NHEADS), 256, 0, stream>>>(qkvb, lens, part);
        if (layer == 0)
            k_projffln<<<MB4, 256, 0, stream>>>(part, x, outT, out_b, ln1_w, ln1_b,
                                                ff1T, ff1_b, ff2T, ff2_b, ln2_w, ln2_b,
                                                x, 0, wtype, wtime, lens);
        else
            k_projffln<<<MB4, 256, 0, stream>>>(part, x, outT, out_b, ln1_w, ln1_b,
                                                ff1T, ff1_b, ff2T, ff2_b, ln2_w, ln2_b,
                                                outp, 1, wtype, wtime, lens);
    }
}